// Round 16
// baseline (188.470 us; speedup 1.0000x reference)
//
#include <hip/hip_runtime.h>
#include <hip/hip_bf16.h>

// Problem constants (SelectSphereConv, graph level 6)
#define VN 40962
#define NGB 5121          // blocks of 8 vertices (512 threads, two half-blocks)
#define LDA_B 1168        // A-tile row stride bytes (576*2 + 16 pad)
#define LDS_TOT 37376     // 32 rows x 1168
#define XT_BYTES (VN * 512)

typedef float f32x4 __attribute__((ext_vector_type(4)));
typedef __bf16 bf16x8 __attribute__((ext_vector_type(8)));

// ---------------------------------------------------------------------------
// Kernel 1: transpose x [256(t=b*64+c), V] f32 -> x_t [V, 256] bf16
// ---------------------------------------------------------------------------
__global__ __launch_bounds__(256) void k_transpose(const float* __restrict__ x,
                                                   __bf16* __restrict__ xt) {
    __shared__ __bf16 tile[64][65];
    const int v0 = blockIdx.x * 64;
    const int t0 = blockIdx.y * 64;
    const int lane = threadIdx.x & 63;
    const int sub = threadIdx.x >> 6;

#pragma unroll
    for (int r = 0; r < 16; ++r) {
        const int t = t0 + r * 4 + sub;
        const int v = v0 + lane;
        float val = (v < VN) ? x[(size_t)t * VN + v] : 0.f;   // coalesced
        tile[r * 4 + sub][lane] = (__bf16)val;
    }
    __syncthreads();
#pragma unroll
    for (int r = 0; r < 16; ++r) {
        const int vv = r * 4 + sub;
        const int v = v0 + vv;
        if (v < VN) xt[(size_t)v * 256 + t0 + lane] = tile[lane][vv];  // coalesced
    }
}

// ---------------------------------------------------------------------------
// Kernel 2: pre-swizzle conv_w into MFMA fragment order (R1/R3-validated):
//   wf[((w*18+ks)*64 + lane)*8 + e] = conv_w[(w*16+(lane&15))*576
//                                            + ks*32 + (lane>>4)*8 + e]
// ---------------------------------------------------------------------------
__global__ __launch_bounds__(64) void k_wprep(const float* __restrict__ conv_w,
                                              __bf16* __restrict__ wf) {
    const int id = blockIdx.x;           // w*18 + ks, 0..71
    const int ks = id % 18;
    const int w  = id / 18;
    const int lane = threadIdx.x;        // 0..63
    const int o  = w * 16 + (lane & 15);
    const int kb = (lane >> 4) * 8;
    const float* wrow = conv_w + (size_t)o * 576 + ks * 32 + kb;
    bf16x8 f;
#pragma unroll
    for (int e = 0; e < 8; ++e) f[e] = (__bf16)wrow[e];
    *(bf16x8*)(wf + ((size_t)id * 64 + lane) * 8) = f;
}

// ---------------------------------------------------------------------------
// Kernel 3: fused gather + interpolate + conv. 512 threads / 8 vertices per
//   block: each 256-thread half-block runs R14's phase-1 VERBATIM on its own
//   4 vertices (no values live across the barrier -> VGPR stays R14-low;
//   R15's in-block pipeline regressed by holding 36 gather regs across MFMA).
//   A-tile 32 rows = 37376 B -> 4 blocks x 8 waves = 32 waves/CU (100% slot
//   cap, vs R14's 24). ONE barrier. MFMA wave w: row-half = w>>2, o-tile =
//   w&3; direct store (R13-validated mapping); bijective XCD swizzle
//   (R14-validated mechanism; 5121 form validated in R15).
//   NO waves-per-EU hint (R8/R9: forcing -> spills).
// ---------------------------------------------------------------------------
__global__ __launch_bounds__(512) void k_fused(const __bf16* __restrict__ xt,
                                               const int* __restrict__ index,
                                               const float* __restrict__ itp_mat,
                                               const __bf16* __restrict__ wf,
                                               const float* __restrict__ conv_b,
                                               float* __restrict__ out) {
    __shared__ char smem[LDS_TOT];

    const int tid  = threadIdx.x;
    const int lane = tid & 63;
    const int w    = tid >> 6;      // wave 0..7
    const int l16  = lane & 15;
    const int g4   = lane >> 4;
    const int half = w >> 2;        // vertex half-group (phase 1), row-half (MFMA)
    const int b    = w & 3;         // batch (phase 1); o-tile (MFMA)

    // ---- bijective XCD swizzle: NGB = 5121 = 8*640 + 1 ----
    // xcd = bid & 7 (HW round-robin): XCD 0 owns [0,641), XCD k>=1 owns
    // [641+(k-1)*640, +640). Bijective on 0..5120; contiguous v per XCD.
    int g;
    {
        const int bid = blockIdx.x;
        const int xcd = bid & 7;
        const int idx = bid >> 3;
        g = (xcd == 0) ? idx : (641 + (xcd - 1) * 640 + idx);
    }
    const int v0 = g * 8;

    // ---------------- phase 1: gather (hoisted) + interpolate --------------
    // half-block h covers vertices v0+4h..+3; thread col t = b*64 + lane.
    float gv[4][9];
#pragma unroll
    for (int vv = 0; vv < 4; ++vv) {
        const int v  = v0 + half * 4 + vv;
        const int vm = (v < VN) ? v : VN - 1;           // clamp tail
        const int* idxv = index + (size_t)vm * 9;       // wave-uniform -> s_load
#pragma unroll
        for (int k = 0; k < 9; ++k)
            gv[vv][k] = (float)xt[(size_t)idxv[k] * 256 + b * 64 + lane];
    }
#pragma unroll
    for (int vv = 0; vv < 4; ++vv) {
        const int v  = v0 + half * 4 + vv;
        const int vm = (v < VN) ? v : VN - 1;
        const float* am = itp_mat + (size_t)vm * 81;    // wave-uniform -> s_load
        float s[9];
#pragma unroll
        for (int j = 0; j < 9; ++j) s[j] = 0.f;
#pragma unroll
        for (int k = 0; k < 9; ++k) {
            const float gk = gv[vv][k];
#pragma unroll
            for (int j = 0; j < 9; ++j) s[j] += gk * am[k * 9 + j];
        }
        // A-tile row = (global vertex slot)*4 + b
        const int row = (half * 4 + vv) * 4 + b;
        __bf16* rowp = (__bf16*)(smem + row * LDA_B) + lane * 9;
#pragma unroll
        for (int j = 0; j < 9; ++j) rowp[j] = (__bf16)s[j];
    }
    __syncthreads();   // the ONLY barrier: A-tile ready

    // ---------------- phase 2: MFMA (A = streamed W, B = itp tile) --------
    // wave w: rows 16*half..+15, o-tile b.
    f32x4 acc = {0.f, 0.f, 0.f, 0.f};
    {
        const char* ar = smem + (16 * half + l16) * LDA_B + g4 * 16;
        const __bf16* wfp = wf + ((size_t)(b * 18) * 64 + lane) * 8;
#pragma unroll
        for (int ks = 0; ks < 18; ++ks) {
            bf16x8 a  = *(const bf16x8*)(ar + ks * 64);
            bf16x8 wb = *(const bf16x8*)(wfp + (size_t)ks * 512);
            acc = __builtin_amdgcn_mfma_f32_16x16x32_bf16(wb, a, acc, 0, 0, 0);
        }
    }

    // ---------------- direct store (R13-validated mapping) ----------------
    // D col = l16 = (vvs = l16>>2 within half, bs = l16&3); D row = o.
    {
        const int vvs = l16 >> 2;
        const int bs  = l16 & 3;
        const int v_s = v0 + half * 4 + vvs;
        const int o_b = b * 16 + g4 * 4;
        const f32x4 bias4 = *(const f32x4*)(conv_b + o_b);   // 16B-aligned
        if (v_s < VN) {
            float* ob = out + (size_t)(bs * 64 + o_b) * VN + v_s;
#pragma unroll
            for (int r = 0; r < 4; ++r)
                ob[(size_t)r * VN] = acc[r] + bias4[r];
        }
    }
}

// ---------------------------------------------------------------------------
extern "C" void kernel_launch(void* const* d_in, const int* in_sizes, int n_in,
                              void* d_out, int out_size, void* d_ws, size_t ws_size,
                              hipStream_t stream) {
    const float* x       = (const float*)d_in[0];
    const int*   index   = (const int*)d_in[1];
    const float* itp_mat = (const float*)d_in[2];
    const float* conv_w  = (const float*)d_in[3];
    const float* conv_b  = (const float*)d_in[4];
    float* out = (float*)d_out;

    __bf16* xt = (__bf16*)d_ws;                          // 20,972,544 B
    __bf16* wfrag = (__bf16*)((char*)d_ws + XT_BYTES);   // + 73,728 B

    dim3 tgrid((VN + 63) / 64, 4, 1);
    k_transpose<<<tgrid, 256, 0, stream>>>(x, xt);
    k_wprep<<<72, 64, 0, stream>>>(conv_w, wfrag);
    k_fused<<<NGB, 512, 0, stream>>>(xt, index, itp_mat, wfrag, conv_b, out);
}

// Round 17
// 89.647 us; speedup vs baseline: 2.1024x; 2.1024x over previous
//
#include <hip/hip_runtime.h>
#include <hip/hip_bf16.h>

// Problem constants (SelectSphereConv, graph level 6)
#define VN 40962
#define NG 10241          // groups of 4 vertices, one per block
#define LDA_B 1168        // A-tile row stride bytes (576*2 + 16 pad)
#define OFF_AM 18688      // am_lds after A-tile: 4 vertices x 84 floats (pad)
#define LDS_TOT 20032     // 18688 + 1344; x8 = 160256 <= 163840 -> 8-block cap
#define XT_BYTES (VN * 512)

typedef float f32x4 __attribute__((ext_vector_type(4)));
typedef __bf16 bf16x8 __attribute__((ext_vector_type(8)));

// ---------------------------------------------------------------------------
// Kernel 1: transpose x [256(t=b*64+c), V] f32 -> x_t [V, 256] bf16
// ---------------------------------------------------------------------------
__global__ __launch_bounds__(256) void k_transpose(const float* __restrict__ x,
                                                   __bf16* __restrict__ xt) {
    __shared__ __bf16 tile[64][65];
    const int v0 = blockIdx.x * 64;
    const int t0 = blockIdx.y * 64;
    const int lane = threadIdx.x & 63;
    const int sub = threadIdx.x >> 6;

#pragma unroll
    for (int r = 0; r < 16; ++r) {
        const int t = t0 + r * 4 + sub;
        const int v = v0 + lane;
        float val = (v < VN) ? x[(size_t)t * VN + v] : 0.f;   // coalesced
        tile[r * 4 + sub][lane] = (__bf16)val;
    }
    __syncthreads();
#pragma unroll
    for (int r = 0; r < 16; ++r) {
        const int vv = r * 4 + sub;
        const int v = v0 + vv;
        if (v < VN) xt[(size_t)v * 256 + t0 + lane] = tile[lane][vv];  // coalesced
    }
}

// ---------------------------------------------------------------------------
// Kernel 2: pre-swizzle conv_w into MFMA fragment order (R1/R3-validated):
//   wf[((w*18+ks)*64 + lane)*8 + e] = conv_w[(w*16+(lane&15))*576
//                                            + ks*32 + (lane>>4)*8 + e]
// ---------------------------------------------------------------------------
__global__ __launch_bounds__(64) void k_wprep(const float* __restrict__ conv_w,
                                              __bf16* __restrict__ wf) {
    const int id = blockIdx.x;           // w*18 + ks, 0..71
    const int ks = id % 18;
    const int w  = id / 18;
    const int lane = threadIdx.x;        // 0..63
    const int o  = w * 16 + (lane & 15);
    const int kb = (lane >> 4) * 8;
    const float* wrow = conv_w + (size_t)o * 576 + ks * 32 + kb;
    bf16x8 f;
#pragma unroll
    for (int e = 0; e < 8; ++e) f[e] = (__bf16)wrow[e];
    *(bf16x8*)(wf + ((size_t)id * 64 + lane) * 8) = f;
}

// ---------------------------------------------------------------------------
// Kernel 3: R14 champion + ONE change: itp_mat coefficients staged to LDS.
//   R14's interp read am[k*9+j] via wave-uniform SCALAR loads; SGPR=80 shows
//   the compiler chunks them interleaved with dependent FMAs -> several
//   serialized ~300cy SMEM round-trips per vertex = the hidden per-block
//   latency chain (wall/block ~30K cy vs ~2.5K modeled; VALU only 26%).
//   Now: wave w vector-loads vertex w's 81 coeffs (coalesced 324B) ->
//   ds_write to am_lds (84-float stride, 16B-aligned) -> raw lgkmcnt-only
//   barrier (gathers stay in flight) -> interp reads broadcast ds_read_b128
//   (uniform addr, conflict-free, pipelined). Static f=4m+e unroll
//   (R5-validated). Everything else is R14 verbatim: direct store
//   (R13 mapping), bijective XCD swizzle (R14: WRITE 103->42MB),
//   A-tile 18688B, no launch-bounds forcing (R8/R9: spills).
// ---------------------------------------------------------------------------
__global__ __launch_bounds__(256) void k_fused(const __bf16* __restrict__ xt,
                                               const int* __restrict__ index,
                                               const float* __restrict__ itp_mat,
                                               const __bf16* __restrict__ wf,
                                               const float* __restrict__ conv_b,
                                               float* __restrict__ out) {
    __shared__ char smem[LDS_TOT];

    const int tid  = threadIdx.x;
    const int lane = tid & 63;
    const int w    = tid >> 6;      // batch b in phase 1; o-tile in MFMA
    const int l16  = lane & 15;
    const int g4   = lane >> 4;

    // ---- bijective XCD swizzle: NG = 10241 = 8*1280 + 1 (R14-validated) ----
    int g;
    {
        const int bid = blockIdx.x;
        const int xcd = bid & 7;
        const int idx = bid >> 3;
        g = (xcd == 0) ? idx : (1281 + (xcd - 1) * 1280 + idx);
    }
    const int v0 = g * 4;

    // ---- stage am: wave w loads vertex (v0+w)'s 81 coeffs (coalesced) ----
    float c0, c1;
    {
        const int vmw = (v0 + w < VN) ? v0 + w : VN - 1;
        const float* amg = itp_mat + (size_t)vmw * 81;
        c0 = amg[lane];
        c1 = (lane < 17) ? amg[64 + lane] : 0.f;
    }

    // ---------------- gathers (all hoisted; R14 verbatim) ----------------
    // thread t = (b = w, c = lane); gathers xt[nb*256 + t] (2B, 128B/wave)
    float gv[4][9];
#pragma unroll
    for (int vv = 0; vv < 4; ++vv) {
        const int v  = v0 + vv;
        const int vm = (v < VN) ? v : VN - 1;           // clamp tail
        const int* idxv = index + (size_t)vm * 9;       // uniform -> s_load
#pragma unroll
        for (int k = 0; k < 9; ++k)
            gv[vv][k] = (float)xt[(size_t)idxv[k] * 256 + tid];
    }

    // ---- write staged am to LDS; make visible w/o draining gathers ----
    {
        float* aml = (float*)(smem + OFF_AM) + w * 84;
        aml[lane] = c0;                       // waits vmcnt for c0 only
        if (lane < 17) aml[64 + lane] = c1;
    }
    asm volatile("s_waitcnt lgkmcnt(0)" ::: "memory");
    __builtin_amdgcn_s_barrier();   // am_lds ready; 36 gathers still in flight

    // ---------------- interp: coeffs via broadcast ds_read_b128 ----------
#pragma unroll
    for (int vv = 0; vv < 4; ++vv) {
        const float* amv = (const float*)(smem + OFF_AM) + vv * 84;
        float s[9];
#pragma unroll
        for (int j = 0; j < 9; ++j) s[j] = 0.f;
#pragma unroll
        for (int m = 0; m < 21; ++m) {
            const f32x4 amc = *(const f32x4*)(amv + m * 4);
#pragma unroll
            for (int e = 0; e < 4; ++e) {
                const int f = 4 * m + e;
                if (f < 81) {
                    const int kk = f / 9, jj = f % 9;
                    s[jj] += gv[vv][kk] * amc[e];
                }
            }
        }
        __bf16* rowp = (__bf16*)(smem + (vv * 4 + w) * LDA_B) + lane * 9;
#pragma unroll
        for (int j = 0; j < 9; ++j) rowp[j] = (__bf16)s[j];
    }
    __syncthreads();   // A-tile ready

    // ---------------- phase 2: MFMA (A = streamed W, B = itp tile) --------
    f32x4 acc = {0.f, 0.f, 0.f, 0.f};
    {
        const char* ar = smem + l16 * LDA_B + g4 * 16;  // B-frag: col=(vv,b)=l16
        const __bf16* wfp = wf + ((size_t)(w * 18) * 64 + lane) * 8;
#pragma unroll
        for (int ks = 0; ks < 18; ++ks) {
            bf16x8 a  = *(const bf16x8*)(ar + ks * 64);
            bf16x8 wb = *(const bf16x8*)(wfp + (size_t)ks * 512);
            acc = __builtin_amdgcn_mfma_f32_16x16x32_bf16(wb, a, acc, 0, 0, 0);
        }
    }

    // ---------------- direct store (R13-validated mapping) ----------------
    // D col = l16 = (vv = l16>>2, b = l16&3); D row = o = w*16 + g4*4 + r.
    {
        const int vvs = l16 >> 2;
        const int bs  = l16 & 3;
        const int v_s = v0 + vvs;
        const int o_b = w * 16 + g4 * 4;
        const f32x4 bias4 = *(const f32x4*)(conv_b + o_b);   // 16B-aligned
        if (v_s < VN) {
            float* ob = out + (size_t)(bs * 64 + o_b) * VN + v_s;
#pragma unroll
            for (int r = 0; r < 4; ++r)
                ob[(size_t)r * VN] = acc[r] + bias4[r];
        }
    }
}

// ---------------------------------------------------------------------------
extern "C" void kernel_launch(void* const* d_in, const int* in_sizes, int n_in,
                              void* d_out, int out_size, void* d_ws, size_t ws_size,
                              hipStream_t stream) {
    const float* x       = (const float*)d_in[0];
    const int*   index   = (const int*)d_in[1];
    const float* itp_mat = (const float*)d_in[2];
    const float* conv_w  = (const float*)d_in[3];
    const float* conv_b  = (const float*)d_in[4];
    float* out = (float*)d_out;

    __bf16* xt = (__bf16*)d_ws;                          // 20,972,544 B
    __bf16* wfrag = (__bf16*)((char*)d_ws + XT_BYTES);   // + 73,728 B

    dim3 tgrid((VN + 63) / 64, 4, 1);
    k_transpose<<<tgrid, 256, 0, stream>>>(x, xt);
    k_wprep<<<72, 64, 0, stream>>>(conv_w, wfrag);
    k_fused<<<NG, 256, 0, stream>>>(xt, index, itp_mat, wfrag, conv_b, out);
}

// Round 18
// 81.277 us; speedup vs baseline: 2.3189x; 1.1030x over previous
//
#include <hip/hip_runtime.h>
#include <hip/hip_bf16.h>

// Problem constants (SelectSphereConv, graph level 6)
#define VN 40962
#define NG 10241          // groups of 4 vertices, one per block
#define LDA_B 1168        // A-tile row stride bytes (576*2 + 16 pad)
#define OFF_AM 18688      // am_lds after A-tile: 4 vertices x 84 floats
#define LDS_TOT 20032     // 18688 + 1344 (same footprint as R17)
#define XT_BYTES (VN * 512)

typedef float f32x4 __attribute__((ext_vector_type(4)));
typedef float f32x2 __attribute__((ext_vector_type(2)));
typedef __bf16 bf16x8 __attribute__((ext_vector_type(8)));

__device__ __forceinline__ float bf16lo(unsigned u) {
    return __builtin_bit_cast(float, u << 16);
}
__device__ __forceinline__ float bf16hi(unsigned u) {
    return __builtin_bit_cast(float, u & 0xffff0000u);
}
__device__ __forceinline__ unsigned bf16b(float x) {
    __bf16 h = (__bf16)x;
    return (unsigned)__builtin_bit_cast(unsigned short, h);
}

// ---------------------------------------------------------------------------
// Kernel 1: transpose x [256(t=b*64+c), V] f32 -> x_t [V, 256] bf16
// ---------------------------------------------------------------------------
__global__ __launch_bounds__(256) void k_transpose(const float* __restrict__ x,
                                                   __bf16* __restrict__ xt) {
    __shared__ __bf16 tile[64][65];
    const int v0 = blockIdx.x * 64;
    const int t0 = blockIdx.y * 64;
    const int lane = threadIdx.x & 63;
    const int sub = threadIdx.x >> 6;

#pragma unroll
    for (int r = 0; r < 16; ++r) {
        const int t = t0 + r * 4 + sub;
        const int v = v0 + lane;
        float val = (v < VN) ? x[(size_t)t * VN + v] : 0.f;   // coalesced
        tile[r * 4 + sub][lane] = (__bf16)val;
    }
    __syncthreads();
#pragma unroll
    for (int r = 0; r < 16; ++r) {
        const int vv = r * 4 + sub;
        const int v = v0 + vv;
        if (v < VN) xt[(size_t)v * 256 + t0 + lane] = tile[lane][vv];  // coalesced
    }
}

// ---------------------------------------------------------------------------
// Kernel 2: pre-swizzle conv_w into MFMA fragment order (R1/R3-validated):
//   wf[((w*18+ks)*64 + lane)*8 + e] = conv_w[(w*16+(lane&15))*576
//                                            + ks*32 + (lane>>4)*8 + e]
// ---------------------------------------------------------------------------
__global__ __launch_bounds__(64) void k_wprep(const float* __restrict__ conv_w,
                                              __bf16* __restrict__ wf) {
    const int id = blockIdx.x;           // w*18 + ks, 0..71
    const int ks = id % 18;
    const int w  = id / 18;
    const int lane = threadIdx.x;        // 0..63
    const int o  = w * 16 + (lane & 15);
    const int kb = (lane >> 4) * 8;
    const float* wrow = conv_w + (size_t)o * 576 + ks * 32 + kb;
    bf16x8 f;
#pragma unroll
    for (int e = 0; e < 8; ++e) f[e] = (__bf16)wrow[e];
    *(bf16x8*)(wf + ((size_t)id * 64 + lane) * 8) = f;
}

// ---------------------------------------------------------------------------
// Kernel 3: R17 + channel-pair PACKED interp. Phase-1 thread = (vh = tid>>7,
//   bb = (tid>>5)&3, p = tid&31 -> channels {2p, 2p+1}); every phase-1 instr
//   class halves: 18 dword gathers (256B/wave/neighbor), 162 v_pk_fma_f32
//   (f32x2 math, VOP3P), 42 am b128 broadcast reads, 18 b32 LDS writes
//   (36B contiguous @ 36p: banks 9p mod 32, conflict-free; bb offset 4 ->
//   2-way free). gd kept as packed dwords (18 regs vs R14's 36 floats) to
//   hold VGPR <= 64 (R10's remap failed at 68 WITHOUT these savings).
//   Everything else R17-verbatim: am-via-LDS + raw lgkm-barrier (gathers in
//   flight), MFMA w/ streamed W, direct store (R13 mapping), bijective XCD
//   swizzle (R14: WRITE 103->42MB). No launch-bounds forcing (R8/R9).
// ---------------------------------------------------------------------------
__global__ __launch_bounds__(256) void k_fused(const __bf16* __restrict__ xt,
                                               const int* __restrict__ index,
                                               const float* __restrict__ itp_mat,
                                               const __bf16* __restrict__ wf,
                                               const float* __restrict__ conv_b,
                                               float* __restrict__ out) {
    __shared__ char smem[LDS_TOT];

    const int tid  = threadIdx.x;
    const int lane = tid & 63;
    const int w    = tid >> 6;      // wave id; o-tile in MFMA
    const int l16  = lane & 15;
    const int g4   = lane >> 4;

    // ---- bijective XCD swizzle: NG = 10241 = 8*1280 + 1 (R14-validated) ----
    int g;
    {
        const int bid = blockIdx.x;
        const int xcd = bid & 7;
        const int idx = bid >> 3;
        g = (xcd == 0) ? idx : (1281 + (xcd - 1) * 1280 + idx);
    }
    const int v0 = g * 4;

    // ---- stage am: wave w loads vertex (v0+w)'s 81 coeffs (coalesced) ----
    float c0, c1;
    {
        const int vmw = (v0 + w < VN) ? v0 + w : VN - 1;
        const float* amg = itp_mat + (size_t)vmw * 81;
        c0 = amg[lane];
        c1 = (lane < 17) ? amg[64 + lane] : 0.f;
    }

    // ---- phase-1 mapping: p = c-pair, bb = batch, vh = vertex parity ----
    const int p  = tid & 31;
    const int bb = (tid >> 5) & 3;
    const int vh = tid >> 7;

    // ---- gathers: 18 dwords (2 vertices x 9 neighbors), all hoisted ----
    unsigned gd[2][9];
#pragma unroll
    for (int vs = 0; vs < 2; ++vs) {
        const int vv = 2 * vs + vh;               // wave-uniform
        const int v  = v0 + vv;
        const int vm = (v < VN) ? v : VN - 1;
        const int* idxv = index + (size_t)vm * 9;       // uniform -> s_load
#pragma unroll
        for (int k = 0; k < 9; ++k)
            gd[vs][k] = *(const unsigned*)(xt + (size_t)idxv[k] * 256 + bb * 64 + 2 * p);
    }

    // ---- write staged am to LDS; visible w/o draining gathers ----
    {
        float* aml = (float*)(smem + OFF_AM) + w * 84;
        aml[lane] = c0;
        if (lane < 17) aml[64 + lane] = c1;
    }
    asm volatile("s_waitcnt lgkmcnt(0)" ::: "memory");
    __builtin_amdgcn_s_barrier();   // am_lds ready; gathers still in flight

    // ---- interp: packed over the channel pair (v_pk_fma_f32) ----
#pragma unroll
    for (int vs = 0; vs < 2; ++vs) {
        const int vv = 2 * vs + vh;
        const float* amv = (const float*)(smem + OFF_AM) + vv * 84;

        f32x2 gk2[9];
#pragma unroll
        for (int k = 0; k < 9; ++k) {
            gk2[k][0] = bf16lo(gd[vs][k]);   // channel 2p
            gk2[k][1] = bf16hi(gd[vs][k]);   // channel 2p+1
        }
        f32x2 sp[9];
#pragma unroll
        for (int j = 0; j < 9; ++j) sp[j] = f32x2{0.f, 0.f};
#pragma unroll
        for (int m = 0; m < 21; ++m) {
            const f32x4 amc = *(const f32x4*)(amv + m * 4);   // broadcast b128
#pragma unroll
            for (int e = 0; e < 4; ++e) {
                const int f = 4 * m + e;
                if (f < 81) {
                    const int kk = f / 9, jj = f % 9;
                    sp[jj] += gk2[kk] * f32x2{amc[e], amc[e]};  // pk_fma
                }
            }
        }
        // pack 18 bf16 (c=2p: j0..8, c=2p+1: j0..8) -> 9 dwords @ byte 36p
        unsigned* wp = (unsigned*)(smem + (size_t)(vv * 4 + bb) * LDA_B + 36 * p);
#pragma unroll
        for (int q = 0; q < 9; ++q) {
            const int t0i = 2 * q, t1i = 2 * q + 1;
            const float e0 = (t0i < 9) ? sp[t0i][0] : sp[t0i - 9][1];
            const float e1 = (t1i < 9) ? sp[t1i][0] : sp[t1i - 9][1];
            wp[q] = bf16b(e0) | (bf16b(e1) << 16);
        }
    }
    __syncthreads();   // A-tile ready

    // ---------------- phase 2: MFMA (A = streamed W, B = itp tile) --------
    f32x4 acc = {0.f, 0.f, 0.f, 0.f};
    {
        const char* ar = smem + l16 * LDA_B + g4 * 16;  // B-frag: col=(vv,b)=l16
        const __bf16* wfp = wf + ((size_t)(w * 18) * 64 + lane) * 8;
#pragma unroll
        for (int ks = 0; ks < 18; ++ks) {
            bf16x8 a  = *(const bf16x8*)(ar + ks * 64);
            bf16x8 wb = *(const bf16x8*)(wfp + (size_t)ks * 512);
            acc = __builtin_amdgcn_mfma_f32_16x16x32_bf16(wb, a, acc, 0, 0, 0);
        }
    }

    // ---------------- direct store (R13-validated mapping) ----------------
    // D col = l16 = (vv = l16>>2, b = l16&3); D row = o = w*16 + g4*4 + r.
    {
        const int vvs = l16 >> 2;
        const int bs  = l16 & 3;
        const int v_s = v0 + vvs;
        const int o_b = w * 16 + g4 * 4;
        const f32x4 bias4 = *(const f32x4*)(conv_b + o_b);   // 16B-aligned
        if (v_s < VN) {
            float* ob = out + (size_t)(bs * 64 + o_b) * VN + v_s;
#pragma unroll
            for (int r = 0; r < 4; ++r)
                ob[(size_t)r * VN] = acc[r] + bias4[r];
        }
    }
}

// ---------------------------------------------------------------------------
extern "C" void kernel_launch(void* const* d_in, const int* in_sizes, int n_in,
                              void* d_out, int out_size, void* d_ws, size_t ws_size,
                              hipStream_t stream) {
    const float* x       = (const float*)d_in[0];
    const int*   index   = (const int*)d_in[1];
    const float* itp_mat = (const float*)d_in[2];
    const float* conv_w  = (const float*)d_in[3];
    const float* conv_b  = (const float*)d_in[4];
    float* out = (float*)d_out;

    __bf16* xt = (__bf16*)d_ws;                          // 20,972,544 B
    __bf16* wfrag = (__bf16*)((char*)d_ws + XT_BYTES);   // + 73,728 B

    dim3 tgrid((VN + 63) / 64, 4, 1);
    k_transpose<<<tgrid, 256, 0, stream>>>(x, xt);
    k_wprep<<<72, 64, 0, stream>>>(conv_w, wfrag);
    k_fused<<<NG, 256, 0, stream>>>(xt, index, itp_mat, wfrag, conv_b, out);
}